// Round 9
// baseline (476.270 us; speedup 1.0000x reference)
//
#include <hip/hip_runtime.h>
#include <hip/hip_cooperative_groups.h>

namespace cg = cooperative_groups;

// GCN encoder, CSR aggregation with separable norm + bf16 gather tables.
//   dinv[i] = rsqrt(deg_in[i]+1)
//   T1 = bf16( dinv * (x@W1) )                       [gemm1, fused scale+quant]
//   T2 = bf16( dinv * relu( dinv*aggsum(T1) + b1 ) ) [agg<0>]
//   T3 = bf16( dinv * aggsum(T2) )                   [agg<1>, reuses T1 buffer]
//   mu = T3@Wmu+bmu ; ls = T3@Wls+bls                [fused dual gemm, bf16 in]
// CSR build: ONE cooperative kernel (hist -> col-scan -> base-scan -> scatter
// -> place), edge chunk cached in LDS across phases. ZERO global atomics.
// aggs are at the compulsory fabric floor (~86MB = 8 XCDs x table once);
// R7 lesson: do not slice interleaved features.

using uint = unsigned int;

static constexpr int FEAT = 64;
static constexpr int BN = 256;          // nodes per bucket (dlocal = 8 bits)
static constexpr int CSR_BLOCKS = 512;  // cooperative grid (2/CU resident)
static constexpr int CHUNK_CAP = 3200;  // >= ceil(E/CSR_BLOCKS) = 3125
static constexpr int NB_MAX = 512;      // max buckets supported in LDS

static __device__ __forceinline__ ushort f2bf(float f) {
    uint u = __float_as_uint(f);
    u += 0x7FFFu + ((u >> 16) & 1u);
    return (ushort)(u >> 16);
}
static __device__ __forceinline__ float bf2f(ushort b) {
    return __uint_as_float(((uint)b) << 16);
}

// Fused CSR build. Block k owns edge chunk k (phases 1,4) and bucket k (2,5).
__global__ __launch_bounds__(256) void csr_build_kernel(const int* __restrict__ src,
                                                        const int* __restrict__ dst,
                                                        int* __restrict__ hist,
                                                        int* __restrict__ btot,
                                                        int* __restrict__ bbase,
                                                        uint* __restrict__ bpk,
                                                        int* __restrict__ rowptr,
                                                        float* __restrict__ dinv,
                                                        int* __restrict__ ssrc,
                                                        int E, int nb, int n) {
    cg::grid_group grid = cg::this_grid();
    __shared__ int2 pairs[CHUNK_CAP];
    __shared__ int h[NB_MAX];
    __shared__ int s2[256];
    __shared__ int cnt[256];
    int k = blockIdx.x;
    int t = threadIdx.x;
    int chunk = (E + CSR_BLOCKS - 1) / CSR_BLOCKS;
    int beg = k * chunk;
    int end = min(beg + chunk, E);
    int cn = (end > beg) ? (end - beg) : 0;

    // phase 1: LDS-cache chunk + histogram
    for (int i = t; i < nb; i += 256) h[i] = 0;
    __syncthreads();
    for (int i = t; i < cn; i += 256) {
        int2 p = make_int2(src[beg + i], dst[beg + i]);
        pairs[i] = p;
        atomicAdd(&h[p.y >> 8], 1);
    }
    __syncthreads();
    for (int i = t; i < nb; i += 256) hist[k * nb + i] = h[i];
    grid.sync();

    // phase 2: per-bucket exclusive scan over CSR_BLOCKS entries (2/thread)
    if (k < nb) {
        int b = k;
        int v0 = hist[(2 * t) * nb + b];
        int v1 = hist[(2 * t + 1) * nb + b];
        int sum = v0 + v1;
        s2[t] = sum; __syncthreads();
        for (int off = 1; off < 256; off <<= 1) {
            int u = (t >= off) ? s2[t - off] : 0;
            __syncthreads();
            s2[t] += u;
            __syncthreads();
        }
        int excl = s2[t] - sum;
        hist[(2 * t) * nb + b] = excl;
        hist[(2 * t + 1) * nb + b] = excl + v0;
        if (t == 255) btot[b] = excl + v0 + v1;
    }
    grid.sync();

    // phase 3: block 0 scans bucket totals -> bbase[0..nb]
    if (k == 0) {
        int i0 = 2 * t, i1 = 2 * t + 1;
        int v0 = (i0 < nb) ? btot[i0] : 0;
        int v1 = (i1 < nb) ? btot[i1] : 0;
        s2[t] = v0 + v1; __syncthreads();
        for (int off = 1; off < 256; off <<= 1) {
            int u = (t >= off) ? s2[t - off] : 0;
            __syncthreads();
            s2[t] += u;
            __syncthreads();
        }
        int excl = s2[t] - (v0 + v1);
        if (i0 <= nb) bbase[i0] = excl;
        if (i1 <= nb) bbase[i1] = excl + v0;
        if (t == 0) rowptr[n] = E;
    }
    grid.sync();

    // phase 4: scatter packed edges from the LDS chunk cache
    for (int i = t; i < nb; i += 256) h[i] = bbase[i] + hist[k * nb + i];
    __syncthreads();
    for (int i = t; i < cn; i += 256) {
        int2 p = pairs[i];
        int pos = atomicAdd(&h[p.y >> 8], 1);
        bpk[pos] = (uint)p.x | ((uint)(p.y & 255) << 17);
    }
    grid.sync();

    // phase 5: place bucket k: in-LDS count -> scan -> rowptr/dinv/ssrc
    if (k < nb) {
        int base = k * BN;
        int pb = bbase[k], pe = bbase[k + 1];
        cnt[t] = 0;
        __syncthreads();
        for (int p = pb + t; p < pe; p += 256)
            atomicAdd(&cnt[bpk[p] >> 17], 1);
        __syncthreads();
        int c = cnt[t];
        s2[t] = c; __syncthreads();
        for (int off = 1; off < 256; off <<= 1) {
            int u = (t >= off) ? s2[t - off] : 0;
            __syncthreads();
            s2[t] += u;
            __syncthreads();
        }
        int excl = pb + s2[t] - c;
        __syncthreads();
        cnt[t] = excl;
        int node = base + t;
        if (node < n) {
            rowptr[node] = excl;
            dinv[node] = rsqrtf((float)c + 1.0f);
        }
        __syncthreads();
        for (int p = pb + t; p < pe; p += 256) {
            uint e = bpk[p];
            int pos = atomicAdd(&cnt[e >> 17], 1);
            ssrc[pos] = (int)(e & 0x1FFFFu);
        }
    }
}

// T1[row][c] = bf16(dinv[row] * (X@W1)[row][c]).  64-row block tile; W and X^T
// staged in LDS; thread computes 4 rows x 4 cols; all LDS reads are b128.
__global__ __launch_bounds__(256) void gemm1_kernel(const float* __restrict__ X,
                                                    const float* __restrict__ W,
                                                    const float* __restrict__ dinv,
                                                    ushort* __restrict__ T1, int n) {
    __shared__ float Ws[128 * 64];
    __shared__ float Xs[128 * 64];
    int tid = threadIdx.x;
    int rowbase = blockIdx.x * 64;
    {
        const float4* Wv = (const float4*)W;
        float4* Wsv = (float4*)Ws;
#pragma unroll
        for (int j = 0; j < 8; ++j) Wsv[tid + 256 * j] = Wv[tid + 256 * j];
    }
    {
        int k4 = (tid & 31) * 4;
        int r0 = tid >> 5;
#pragma unroll
        for (int j = 0; j < 8; ++j) {
            int r = r0 + 8 * j;
            int row = rowbase + r;
            float4 v = make_float4(0.f, 0.f, 0.f, 0.f);
            if (row < n) v = *(const float4*)(X + (size_t)row * 128 + k4);
            Xs[(k4 + 0) * 64 + r] = v.x;
            Xs[(k4 + 1) * 64 + r] = v.y;
            Xs[(k4 + 2) * 64 + r] = v.z;
            Xs[(k4 + 3) * 64 + r] = v.w;
        }
    }
    __syncthreads();
    int lane = tid & 63;
    int wave = tid >> 6;
    int colq = (lane & 15) * 4;
    int rloc = wave * 16 + (lane >> 4) * 4;
    float acc[4][4];
#pragma unroll
    for (int i = 0; i < 4; ++i)
#pragma unroll
        for (int j = 0; j < 4; ++j) acc[i][j] = 0.f;
#pragma unroll 4
    for (int k = 0; k < 128; ++k) {
        float4 w = *(const float4*)&Ws[k * 64 + colq];
        float4 xv = *(const float4*)&Xs[k * 64 + rloc];
        acc[0][0] = fmaf(xv.x, w.x, acc[0][0]); acc[0][1] = fmaf(xv.x, w.y, acc[0][1]);
        acc[0][2] = fmaf(xv.x, w.z, acc[0][2]); acc[0][3] = fmaf(xv.x, w.w, acc[0][3]);
        acc[1][0] = fmaf(xv.y, w.x, acc[1][0]); acc[1][1] = fmaf(xv.y, w.y, acc[1][1]);
        acc[1][2] = fmaf(xv.y, w.z, acc[1][2]); acc[1][3] = fmaf(xv.y, w.w, acc[1][3]);
        acc[2][0] = fmaf(xv.z, w.x, acc[2][0]); acc[2][1] = fmaf(xv.z, w.y, acc[2][1]);
        acc[2][2] = fmaf(xv.z, w.z, acc[2][2]); acc[2][3] = fmaf(xv.z, w.w, acc[2][3]);
        acc[3][0] = fmaf(xv.w, w.x, acc[3][0]); acc[3][1] = fmaf(xv.w, w.y, acc[3][1]);
        acc[3][2] = fmaf(xv.w, w.z, acc[3][2]); acc[3][3] = fmaf(xv.w, w.w, acc[3][3]);
    }
#pragma unroll
    for (int i = 0; i < 4; ++i) {
        int row = rowbase + rloc + i;
        if (row < n) {
            float di = dinv[row];
            ushort4 t;
            t.x = f2bf(acc[i][0] * di);
            t.y = f2bf(acc[i][1] * di);
            t.z = f2bf(acc[i][2] * di);
            t.w = f2bf(acc[i][3] * di);
            *(ushort4*)(T1 + (size_t)row * FEAT + colq) = t;
        }
    }
}

// One wave per node; 64 lanes = 64 feats. Gathers 128B bf16 rows, fp32 accum.
// 8-deep unrolled gather pipeline; ssrc read as wave-uniform int4.
// MODE 0: Tout = bf16(dinv*relu(dinv*sum + bias)); MODE 1: Tout = bf16(dinv*sum).
template<int MODE>
__global__ __launch_bounds__(256) void agg_kernel(const ushort* __restrict__ T,
                                                  const int* __restrict__ rowptr,
                                                  const int* __restrict__ ssrc,
                                                  const float* __restrict__ dinv,
                                                  const float* __restrict__ bias,
                                                  ushort* __restrict__ Tout, int n) {
    int node = blockIdx.x * 4 + (threadIdx.x >> 6);
    if (node >= n) return;
    int f = threadIdx.x & 63;
    int beg = rowptr[node], end = rowptr[node + 1];
    float di = dinv[node];
    float acc = bf2f(T[(size_t)node * FEAT + f]);   // self-loop term
    int p = beg;
    int ahead = (beg + 3) & ~3;                     // align to int4 boundary
    for (int lim = min(ahead, end); p < lim; ++p)
        acc += bf2f(T[(size_t)ssrc[p] * FEAT + f]);
    for (; p + 8 <= end; p += 8) {
        int4 a = *(const int4*)(ssrc + p);
        int4 b = *(const int4*)(ssrc + p + 4);
        float v0 = bf2f(T[(size_t)a.x * FEAT + f]);
        float v1 = bf2f(T[(size_t)a.y * FEAT + f]);
        float v2 = bf2f(T[(size_t)a.z * FEAT + f]);
        float v3 = bf2f(T[(size_t)a.w * FEAT + f]);
        float v4 = bf2f(T[(size_t)b.x * FEAT + f]);
        float v5 = bf2f(T[(size_t)b.y * FEAT + f]);
        float v6 = bf2f(T[(size_t)b.z * FEAT + f]);
        float v7 = bf2f(T[(size_t)b.w * FEAT + f]);
        acc += ((v0 + v1) + (v2 + v3)) + ((v4 + v5) + (v6 + v7));
    }
    if (p + 4 <= end) {
        int4 a = *(const int4*)(ssrc + p);
        float v0 = bf2f(T[(size_t)a.x * FEAT + f]);
        float v1 = bf2f(T[(size_t)a.y * FEAT + f]);
        float v2 = bf2f(T[(size_t)a.z * FEAT + f]);
        float v3 = bf2f(T[(size_t)a.w * FEAT + f]);
        acc += (v0 + v1) + (v2 + v3);
        p += 4;
    }
    for (; p < end; ++p) acc += bf2f(T[(size_t)ssrc[p] * FEAT + f]);
    if (MODE == 0) {
        float h = fmaf(di, acc, bias[f]);
        h = fmaxf(h, 0.0f);
        Tout[(size_t)node * FEAT + f] = f2bf(h * di);
    } else {
        Tout[(size_t)node * FEAT + f] = f2bf(di * acc);
    }
}

// mu = H@Wmu+bmu, ls = H@Wls+bls, H in bf16. 64-row tile, weights + H^T in LDS.
__global__ __launch_bounds__(256) void gemm_dual_kernel(const ushort* __restrict__ H,
                                                        const float* __restrict__ Wmu,
                                                        const float* __restrict__ bmu,
                                                        const float* __restrict__ Wls,
                                                        const float* __restrict__ bls,
                                                        float* __restrict__ mu,
                                                        float* __restrict__ ls, int n) {
    __shared__ float Wm[64 * 64];
    __shared__ float Wl[64 * 64];
    __shared__ float Xs[64 * 64];
    int tid = threadIdx.x;
    int rowbase = blockIdx.x * 64;
    {
        const float4* a = (const float4*)Wmu;
        const float4* b = (const float4*)Wls;
        float4* as = (float4*)Wm;
        float4* bs = (float4*)Wl;
#pragma unroll
        for (int j = 0; j < 4; ++j) { as[tid + 256 * j] = a[tid + 256 * j]; bs[tid + 256 * j] = b[tid + 256 * j]; }
    }
    {
        int k4 = (tid & 15) * 4;
        int r0 = tid >> 4;
#pragma unroll
        for (int j = 0; j < 4; ++j) {
            int r = r0 + 16 * j;
            int row = rowbase + r;
            ushort4 v = make_ushort4(0, 0, 0, 0);
            if (row < n) v = *(const ushort4*)(H + (size_t)row * 64 + k4);
            Xs[(k4 + 0) * 64 + r] = bf2f(v.x);
            Xs[(k4 + 1) * 64 + r] = bf2f(v.y);
            Xs[(k4 + 2) * 64 + r] = bf2f(v.z);
            Xs[(k4 + 3) * 64 + r] = bf2f(v.w);
        }
    }
    __syncthreads();
    int lane = tid & 63;
    int wave = tid >> 6;
    int colq = (lane & 15) * 4;
    int rloc = wave * 16 + (lane >> 4) * 4;
    float am[4][4], al[4][4];
#pragma unroll
    for (int i = 0; i < 4; ++i)
#pragma unroll
        for (int j = 0; j < 4; ++j) { am[i][j] = 0.f; al[i][j] = 0.f; }
#pragma unroll 4
    for (int k = 0; k < 64; ++k) {
        float4 wm = *(const float4*)&Wm[k * 64 + colq];
        float4 wl = *(const float4*)&Wl[k * 64 + colq];
        float4 xv = *(const float4*)&Xs[k * 64 + rloc];
        am[0][0] = fmaf(xv.x, wm.x, am[0][0]); am[0][1] = fmaf(xv.x, wm.y, am[0][1]);
        am[0][2] = fmaf(xv.x, wm.z, am[0][2]); am[0][3] = fmaf(xv.x, wm.w, am[0][3]);
        am[1][0] = fmaf(xv.y, wm.x, am[1][0]); am[1][1] = fmaf(xv.y, wm.y, am[1][1]);
        am[1][2] = fmaf(xv.y, wm.z, am[1][2]); am[1][3] = fmaf(xv.y, wm.w, am[1][3]);
        am[2][0] = fmaf(xv.z, wm.x, am[2][0]); am[2][1] = fmaf(xv.z, wm.y, am[2][1]);
        am[2][2] = fmaf(xv.z, wm.z, am[2][2]); am[2][3] = fmaf(xv.z, wm.w, am[2][3]);
        am[3][0] = fmaf(xv.w, wm.x, am[3][0]); am[3][1] = fmaf(xv.w, wm.y, am[3][1]);
        am[3][2] = fmaf(xv.w, wm.z, am[3][2]); am[3][3] = fmaf(xv.w, wm.w, am[3][3]);
        al[0][0] = fmaf(xv.x, wl.x, al[0][0]); al[0][1] = fmaf(xv.x, wl.y, al[0][1]);
        al[0][2] = fmaf(xv.x, wl.z, al[0][2]); al[0][3] = fmaf(xv.x, wl.w, al[0][3]);
        al[1][0] = fmaf(xv.y, wl.x, al[1][0]); al[1][1] = fmaf(xv.y, wl.y, al[1][1]);
        al[1][2] = fmaf(xv.y, wl.z, al[1][2]); al[1][3] = fmaf(xv.y, wl.w, al[1][3]);
        al[2][0] = fmaf(xv.z, wl.x, al[2][0]); al[2][1] = fmaf(xv.z, wl.y, al[2][1]);
        al[2][2] = fmaf(xv.z, wl.z, al[2][2]); al[2][3] = fmaf(xv.z, wl.w, al[2][3]);
        al[3][0] = fmaf(xv.w, wl.x, al[3][0]); al[3][1] = fmaf(xv.w, wl.y, al[3][1]);
        al[3][2] = fmaf(xv.w, wl.z, al[3][2]); al[3][3] = fmaf(xv.w, wl.w, al[3][3]);
    }
    float4 bm = *(const float4*)&bmu[colq];
    float4 bl = *(const float4*)&bls[colq];
#pragma unroll
    for (int i = 0; i < 4; ++i) {
        int row = rowbase + rloc + i;
        if (row < n) {
            *(float4*)(mu + (size_t)row * 64 + colq) =
                make_float4(am[i][0] + bm.x, am[i][1] + bm.y, am[i][2] + bm.z, am[i][3] + bm.w);
            *(float4*)(ls + (size_t)row * 64 + colq) =
                make_float4(al[i][0] + bl.x, al[i][1] + bl.y, al[i][2] + bl.z, al[i][3] + bl.w);
        }
    }
}

extern "C" void kernel_launch(void* const* d_in, const int* in_sizes, int n_in,
                              void* d_out, int out_size, void* d_ws, size_t ws_size,
                              hipStream_t stream) {
    const float* x   = (const float*)d_in[0];
    const int*   ei  = (const int*)d_in[1];
    const float* W1  = (const float*)d_in[2];
    const float* b1  = (const float*)d_in[3];
    const float* Wmu = (const float*)d_in[4];
    const float* bmu = (const float*)d_in[5];
    const float* Wls = (const float*)d_in[6];
    const float* bls = (const float*)d_in[7];

    const int N = in_sizes[0] / 128;
    const int E = in_sizes[1] / 2;
    const int* src = ei;
    const int* dst = ei + E;

    const int nb = (N + BN - 1) / BN;   // 391 buckets (<= NB_MAX)

    float*  dinv   = (float*)d_ws;                      // N
    int*    rowptr = (int*)(dinv + N);                  // N+1
    int*    hist   = rowptr + ((N + 1 + 63) & ~63);     // CSR_BLOCKS*nb
    int*    btot   = hist + CSR_BLOCKS * nb;            // nb
    int*    bbase  = btot + ((nb + 63) & ~63);          // nb+1
    int*    ssrc   = bbase + ((nb + 1 + 63) & ~63);     // E
    uint*   bpk    = (uint*)(ssrc + E);                 // E
    ushort* T1     = (ushort*)(bpk + E);                // N*64 bf16 (T1, then T3)
    ushort* T2     = T1 + (size_t)N * FEAT;             // N*64 bf16

    float* mu_out = (float*)d_out;                      // N*64
    float* ls_out = mu_out + (size_t)N * FEAT;          // N*64

    const int TB = 256;
    int grid_n4 = (N + 3) / 4;
    int grid_g  = (N + 63) / 64;

    // ---- fused CSR build (cooperative: 5 phases, 4 grid.syncs) ----
    {
        int E_ = E, nb_ = nb, n_ = N;
        const int* src_ = src; const int* dst_ = dst;
        int* hist_ = hist; int* btot_ = btot; int* bbase_ = bbase;
        uint* bpk_ = bpk; int* rowptr_ = rowptr; float* dinv_ = dinv; int* ssrc_ = ssrc;
        void* args[] = { &src_, &dst_, &hist_, &btot_, &bbase_, &bpk_,
                         &rowptr_, &dinv_, &ssrc_, &E_, &nb_, &n_ };
        hipLaunchCooperativeKernel((const void*)csr_build_kernel,
                                   dim3(CSR_BLOCKS), dim3(TB), args, 0, stream);
    }

    // ---- T1 = bf16(dinv * (x@W1)) ----
    gemm1_kernel<<<grid_g, TB, 0, stream>>>(x, W1, dinv, T1, N);

    // ---- T2 = bf16(dinv * relu(dinv*aggsum(T1) + b1)) ----
    agg_kernel<0><<<grid_n4, TB, 0, stream>>>(T1, rowptr, ssrc, dinv, b1, T2, N);

    // ---- T3 = bf16(dinv * aggsum(T2))  (reuses T1 buffer) ----
    agg_kernel<1><<<grid_n4, TB, 0, stream>>>(T2, rowptr, ssrc, dinv, nullptr, T1, N);

    // ---- heads: mu/ls from bf16 T3 ----
    gemm_dual_kernel<<<grid_g, TB, 0, stream>>>(T1, Wmu, bmu, Wls, bls, mu_out, ls_out, N);
}

// Round 10
// 217.108 us; speedup vs baseline: 2.1937x; 2.1937x over previous
//
#include <hip/hip_runtime.h>

// GCN encoder, CSR aggregation with separable norm + bf16 gather tables.
//   dinv[i] = rsqrt(deg_in[i]+1)
//   T1 = bf16( dinv * (x@W1) )                       [MFMA gemm1, fused scale+quant]
//   T2 = bf16( dinv * relu( dinv*aggsum(T1) + b1 ) ) [agg<0>]
//   T3 = bf16( dinv * aggsum(T2) )                   [agg<1>, reuses T1 buffer]
//   mu = T3@Wmu+bmu ; ls = T3@Wls+bls                [MFMA dual gemm]
// CSR build: contention-free counting sort (R6 structure — per-block LDS
// histograms, per-bucket scan, private dense regions, per-bucket place).
// Lessons kept: no global-cursor atomics (R4), no interleaved feature slices
// (R7), no cooperative mega-kernel / column-strided RMW false sharing (R9).
// aggs are at the compulsory fabric floor (~86MB = 8 XCDs x table once).

using uint = unsigned int;

static constexpr int FEAT = 64;
static constexpr int BN = 256;          // nodes per bucket (dlocal = 8 bits)
static constexpr int SORT_BLOCKS = 256; // edge chunks
static constexpr int NB_MAX = 512;      // max buckets supported in LDS

typedef __attribute__((ext_vector_type(8))) short bf16x8;
typedef __attribute__((ext_vector_type(4))) float f32x4;

static __device__ __forceinline__ ushort f2bf(float f) {
    uint u = __float_as_uint(f);
    u += 0x7FFFu + ((u >> 16) & 1u);
    return (ushort)(u >> 16);
}
static __device__ __forceinline__ float bf2f(ushort b) {
    return __uint_as_float(((uint)b) << 16);
}

// ---------------- CSR build (R6 structure) ----------------

__global__ __launch_bounds__(256) void hist_kernel(const int* __restrict__ dst,
                                                   int* __restrict__ hist, int E, int nb) {
    __shared__ int h[NB_MAX];
    for (int i = threadIdx.x; i < nb; i += 256) h[i] = 0;
    __syncthreads();
    int chunk = (E + SORT_BLOCKS - 1) / SORT_BLOCKS;
    int beg = blockIdx.x * chunk;
    int end = min(beg + chunk, E);
    for (int e = beg + (int)threadIdx.x; e < end; e += 256)
        atomicAdd(&h[dst[e] >> 8], 1);
    __syncthreads();
    for (int i = threadIdx.x; i < nb; i += 256) hist[blockIdx.x * nb + i] = h[i];
}

__global__ __launch_bounds__(256) void colscan_kernel(int* __restrict__ hist,
                                                      int* __restrict__ btot, int nb) {
    __shared__ int s[256];
    int b = blockIdx.x;
    int t = threadIdx.x;
    int v = hist[t * nb + b];
    s[t] = v; __syncthreads();
    for (int off = 1; off < 256; off <<= 1) {
        int u = (t >= off) ? s[t - off] : 0;
        __syncthreads();
        s[t] += u;
        __syncthreads();
    }
    hist[t * nb + b] = s[t] - v;      // exclusive within bucket
    if (t == 255) btot[b] = s[255];
}

__global__ __launch_bounds__(256) void bbase_kernel(const int* __restrict__ btot,
                                                    int* __restrict__ bbase, int nb,
                                                    int* __restrict__ rowptr, int n, int E) {
    __shared__ int s[256];
    int t = threadIdx.x;
    int i0 = 2 * t, i1 = 2 * t + 1;
    int v0 = (i0 < nb) ? btot[i0] : 0;
    int v1 = (i1 < nb) ? btot[i1] : 0;
    s[t] = v0 + v1; __syncthreads();
    for (int off = 1; off < 256; off <<= 1) {
        int u = (t >= off) ? s[t - off] : 0;
        __syncthreads();
        s[t] += u;
        __syncthreads();
    }
    int excl = s[t] - (v0 + v1);
    if (i0 < nb) bbase[i0] = excl;
    if (i1 < nb) bbase[i1] = excl + v0;
    if (i0 == nb) bbase[nb] = excl;
    else if (i1 == nb) bbase[nb] = excl + v0;
    if (t == 0) rowptr[n] = E;
}

__global__ __launch_bounds__(256) void sort_scatter_kernel(const int* __restrict__ src,
                                                           const int* __restrict__ dst,
                                                           const int* __restrict__ hist,
                                                           const int* __restrict__ bbase,
                                                           uint* __restrict__ bpk, int E, int nb) {
    __shared__ int cur[NB_MAX];
    int k = blockIdx.x;
    for (int i = threadIdx.x; i < nb; i += 256) cur[i] = bbase[i] + hist[k * nb + i];
    __syncthreads();
    int chunk = (E + SORT_BLOCKS - 1) / SORT_BLOCKS;
    int beg = k * chunk;
    int end = min(beg + chunk, E);
    for (int e = beg + (int)threadIdx.x; e < end; e += 256) {
        int s = src[e], d = dst[e];
        int pos = atomicAdd(&cur[d >> 8], 1);
        bpk[pos] = (uint)s | ((uint)(d & 255) << 17);
    }
}

__global__ __launch_bounds__(256) void place_kernel(const uint* __restrict__ bpk,
                                                    const int* __restrict__ bbase,
                                                    int* __restrict__ rowptr,
                                                    float* __restrict__ dinv,
                                                    int* __restrict__ ssrc, int n) {
    __shared__ int cnt[BN];
    __shared__ int s[256];
    int b = blockIdx.x;
    int base = b * BN;
    int beg = bbase[b], end = bbase[b + 1];
    cnt[threadIdx.x] = 0;
    __syncthreads();
    for (int p = beg + (int)threadIdx.x; p < end; p += 256)
        atomicAdd(&cnt[bpk[p] >> 17], 1);
    __syncthreads();
    int c = cnt[threadIdx.x];
    s[threadIdx.x] = c; __syncthreads();
    for (int off = 1; off < 256; off <<= 1) {
        int u = (threadIdx.x >= off) ? s[threadIdx.x - off] : 0;
        __syncthreads();
        s[threadIdx.x] += u;
        __syncthreads();
    }
    int excl = beg + s[threadIdx.x] - c;
    __syncthreads();
    cnt[threadIdx.x] = excl;              // becomes the write cursor
    int node = base + threadIdx.x;
    if (node < n) {
        rowptr[node] = excl;
        dinv[node] = rsqrtf((float)c + 1.0f);
    }
    __syncthreads();
    for (int p = beg + (int)threadIdx.x; p < end; p += 256) {
        uint e = bpk[p];
        int pos = atomicAdd(&cnt[e >> 17], 1);
        ssrc[pos] = (int)(e & 0x1FFFFu);
    }
}

// ---------------- weight prep: transpose + bf16 ----------------
// w1t[n][k] = bf16(W1[k][n]) (64x128); wmt/wlt[n][k] (64x64).
__global__ __launch_bounds__(256) void prep_w_kernel(const float* __restrict__ W1,
                                                     const float* __restrict__ Wmu,
                                                     const float* __restrict__ Wls,
                                                     ushort* __restrict__ w1t,
                                                     ushort* __restrict__ wmt,
                                                     ushort* __restrict__ wlt) {
    int t = blockIdx.x * 256 + threadIdx.x;
    for (int idx = t; idx < 64 * 128; idx += 2048) {
        int nn = idx >> 7, kk = idx & 127;
        w1t[idx] = f2bf(W1[kk * 64 + nn]);
    }
    for (int idx = t; idx < 64 * 64; idx += 2048) {
        int nn = idx >> 6, kk = idx & 63;
        wmt[idx] = f2bf(Wmu[kk * 64 + nn]);
        wlt[idx] = f2bf(Wls[kk * 64 + nn]);
    }
}

// ---------------- MFMA gemm1: T1 = bf16(dinv * (X@W1)) ----------------
// Block = 4 waves; wave w owns rows [blk*64+w*16, +16) x 64 cols.
// A-frag: lane&15 = local row, (lane>>4,j) = k-slot; B-frag: lane&15 = col,
// same k-slot mapping (slot-consistency makes the exact k permutation moot).
// C/D layout (HW-verified): col = lane&15, row = (lane>>4)*4 + reg.
__global__ __launch_bounds__(256) void gemm1_kernel(const float* __restrict__ X,
                                                    const ushort* __restrict__ Wt,
                                                    const float* __restrict__ dinv,
                                                    ushort* __restrict__ T1, int n) {
    int lane = threadIdx.x & 63;
    int w = threadIdx.x >> 6;
    int rowbase = blockIdx.x * 64 + w * 16;
    int nl = lane & 15;
    int kg = lane >> 4;
    int arow = min(rowbase + nl, n - 1);
    const float* xr = X + (size_t)arow * 128 + kg * 8;
    f32x4 acc0 = {0.f, 0.f, 0.f, 0.f};
    f32x4 acc1 = acc0, acc2 = acc0, acc3 = acc0;
#pragma unroll
    for (int ks = 0; ks < 4; ++ks) {
        int k0 = ks * 32;
        float4 xa = *(const float4*)(xr + k0);
        float4 xb = *(const float4*)(xr + k0 + 4);
        bf16x8 a;
        a[0] = (short)f2bf(xa.x); a[1] = (short)f2bf(xa.y);
        a[2] = (short)f2bf(xa.z); a[3] = (short)f2bf(xa.w);
        a[4] = (short)f2bf(xb.x); a[5] = (short)f2bf(xb.y);
        a[6] = (short)f2bf(xb.z); a[7] = (short)f2bf(xb.w);
        const ushort* wb = Wt + (size_t)nl * 128 + k0 + kg * 8;
        bf16x8 b0 = *(const bf16x8*)(wb);
        bf16x8 b1 = *(const bf16x8*)(wb + 16 * 128);
        bf16x8 b2 = *(const bf16x8*)(wb + 32 * 128);
        bf16x8 b3 = *(const bf16x8*)(wb + 48 * 128);
        acc0 = __builtin_amdgcn_mfma_f32_16x16x32_bf16(a, b0, acc0, 0, 0, 0);
        acc1 = __builtin_amdgcn_mfma_f32_16x16x32_bf16(a, b1, acc1, 0, 0, 0);
        acc2 = __builtin_amdgcn_mfma_f32_16x16x32_bf16(a, b2, acc2, 0, 0, 0);
        acc3 = __builtin_amdgcn_mfma_f32_16x16x32_bf16(a, b3, acc3, 0, 0, 0);
    }
#pragma unroll
    for (int r = 0; r < 4; ++r) {
        int row = rowbase + kg * 4 + r;
        if (row < n) {
            float di = dinv[row];
            ushort* out = T1 + (size_t)row * FEAT + nl;
            out[0]  = f2bf(acc0[r] * di);
            out[16] = f2bf(acc1[r] * di);
            out[32] = f2bf(acc2[r] * di);
            out[48] = f2bf(acc3[r] * di);
        }
    }
}

// ---------------- aggregation (R6/R8 form, at fabric floor) ----------------
template<int MODE>
__global__ __launch_bounds__(256) void agg_kernel(const ushort* __restrict__ T,
                                                  const int* __restrict__ rowptr,
                                                  const int* __restrict__ ssrc,
                                                  const float* __restrict__ dinv,
                                                  const float* __restrict__ bias,
                                                  ushort* __restrict__ Tout, int n) {
    int node = blockIdx.x * 4 + (threadIdx.x >> 6);
    if (node >= n) return;
    int f = threadIdx.x & 63;
    int beg = rowptr[node], end = rowptr[node + 1];
    float di = dinv[node];
    float acc = bf2f(T[(size_t)node * FEAT + f]);   // self-loop term
    int p = beg;
    int ahead = (beg + 3) & ~3;                     // align to int4 boundary
    for (int lim = min(ahead, end); p < lim; ++p)
        acc += bf2f(T[(size_t)ssrc[p] * FEAT + f]);
    for (; p + 8 <= end; p += 8) {
        int4 a = *(const int4*)(ssrc + p);
        int4 b = *(const int4*)(ssrc + p + 4);
        float v0 = bf2f(T[(size_t)a.x * FEAT + f]);
        float v1 = bf2f(T[(size_t)a.y * FEAT + f]);
        float v2 = bf2f(T[(size_t)a.z * FEAT + f]);
        float v3 = bf2f(T[(size_t)a.w * FEAT + f]);
        float v4 = bf2f(T[(size_t)b.x * FEAT + f]);
        float v5 = bf2f(T[(size_t)b.y * FEAT + f]);
        float v6 = bf2f(T[(size_t)b.z * FEAT + f]);
        float v7 = bf2f(T[(size_t)b.w * FEAT + f]);
        acc += ((v0 + v1) + (v2 + v3)) + ((v4 + v5) + (v6 + v7));
    }
    if (p + 4 <= end) {
        int4 a = *(const int4*)(ssrc + p);
        float v0 = bf2f(T[(size_t)a.x * FEAT + f]);
        float v1 = bf2f(T[(size_t)a.y * FEAT + f]);
        float v2 = bf2f(T[(size_t)a.z * FEAT + f]);
        float v3 = bf2f(T[(size_t)a.w * FEAT + f]);
        acc += (v0 + v1) + (v2 + v3);
        p += 4;
    }
    for (; p < end; ++p) acc += bf2f(T[(size_t)ssrc[p] * FEAT + f]);
    if (MODE == 0) {
        float h = fmaf(di, acc, bias[f]);
        h = fmaxf(h, 0.0f);
        Tout[(size_t)node * FEAT + f] = f2bf(h * di);
    } else {
        Tout[(size_t)node * FEAT + f] = f2bf(di * acc);
    }
}

// ---------------- MFMA dual head: mu/ls = H@W + b (H bf16) ----------------
__global__ __launch_bounds__(256) void gemm_dual_kernel(const ushort* __restrict__ H,
                                                        const ushort* __restrict__ Wmt,
                                                        const float* __restrict__ bmu,
                                                        const ushort* __restrict__ Wlt,
                                                        const float* __restrict__ bls,
                                                        float* __restrict__ mu,
                                                        float* __restrict__ ls, int n) {
    int lane = threadIdx.x & 63;
    int w = threadIdx.x >> 6;
    int rowbase = blockIdx.x * 64 + w * 16;
    int nl = lane & 15;
    int kg = lane >> 4;
    int arow = min(rowbase + nl, n - 1);
    const ushort* hr = H + (size_t)arow * 64 + kg * 8;
    f32x4 am0 = {0.f, 0.f, 0.f, 0.f};
    f32x4 am1 = am0, am2 = am0, am3 = am0;
    f32x4 al0 = am0, al1 = am0, al2 = am0, al3 = am0;
#pragma unroll
    for (int ks = 0; ks < 2; ++ks) {
        int k0 = ks * 32;
        bf16x8 a = *(const bf16x8*)(hr + k0);
        const ushort* wm = Wmt + (size_t)nl * 64 + k0 + kg * 8;
        const ushort* wl = Wlt + (size_t)nl * 64 + k0 + kg * 8;
        bf16x8 m0 = *(const bf16x8*)(wm);
        bf16x8 m1 = *(const bf16x8*)(wm + 16 * 64);
        bf16x8 m2 = *(const bf16x8*)(wm + 32 * 64);
        bf16x8 m3 = *(const bf16x8*)(wm + 48 * 64);
        bf16x8 l0 = *(const bf16x8*)(wl);
        bf16x8 l1 = *(const bf16x8*)(wl + 16 * 64);
        bf16x8 l2 = *(const bf16x8*)(wl + 32 * 64);
        bf16x8 l3 = *(const bf16x8*)(wl + 48 * 64);
        am0 = __builtin_amdgcn_mfma_f32_16x16x32_bf16(a, m0, am0, 0, 0, 0);
        am1 = __builtin_amdgcn_mfma_f32_16x16x32_bf16(a, m1, am1, 0, 0, 0);
        am2 = __builtin_amdgcn_mfma_f32_16x16x32_bf16(a, m2, am2, 0, 0, 0);
        am3 = __builtin_amdgcn_mfma_f32_16x16x32_bf16(a, m3, am3, 0, 0, 0);
        al0 = __builtin_amdgcn_mfma_f32_16x16x32_bf16(a, l0, al0, 0, 0, 0);
        al1 = __builtin_amdgcn_mfma_f32_16x16x32_bf16(a, l1, al1, 0, 0, 0);
        al2 = __builtin_amdgcn_mfma_f32_16x16x32_bf16(a, l2, al2, 0, 0, 0);
        al3 = __builtin_amdgcn_mfma_f32_16x16x32_bf16(a, l3, al3, 0, 0, 0);
    }
    float bm0 = bmu[nl], bm1 = bmu[16 + nl], bm2 = bmu[32 + nl], bm3 = bmu[48 + nl];
    float bl0 = bls[nl], bl1 = bls[16 + nl], bl2 = bls[32 + nl], bl3 = bls[48 + nl];
#pragma unroll
    for (int r = 0; r < 4; ++r) {
        int row = rowbase + kg * 4 + r;
        if (row < n) {
            float* om = mu + (size_t)row * 64 + nl;
            float* ol = ls + (size_t)row * 64 + nl;
            om[0]  = am0[r] + bm0; om[16] = am1[r] + bm1;
            om[32] = am2[r] + bm2; om[48] = am3[r] + bm3;
            ol[0]  = al0[r] + bl0; ol[16] = al1[r] + bl1;
            ol[32] = al2[r] + bl2; ol[48] = al3[r] + bl3;
        }
    }
}

extern "C" void kernel_launch(void* const* d_in, const int* in_sizes, int n_in,
                              void* d_out, int out_size, void* d_ws, size_t ws_size,
                              hipStream_t stream) {
    const float* x   = (const float*)d_in[0];
    const int*   ei  = (const int*)d_in[1];
    const float* W1  = (const float*)d_in[2];
    const float* b1  = (const float*)d_in[3];
    const float* Wmu = (const float*)d_in[4];
    const float* bmu = (const float*)d_in[5];
    const float* Wls = (const float*)d_in[6];
    const float* bls = (const float*)d_in[7];

    const int N = in_sizes[0] / 128;
    const int E = in_sizes[1] / 2;
    const int* src = ei;
    const int* dst = ei + E;

    const int nb = (N + BN - 1) / BN;   // 391 buckets (<= NB_MAX)

    float*  dinv   = (float*)d_ws;                      // N
    int*    rowptr = (int*)(dinv + N);                  // N+1 (padded)
    int*    hist   = rowptr + ((N + 1 + 63) & ~63);     // SORT_BLOCKS*nb
    int*    btot   = hist + SORT_BLOCKS * nb;           // nb (padded)
    int*    bbase  = btot + ((nb + 63) & ~63);          // nb+1 (padded)
    int*    ssrc   = bbase + ((nb + 1 + 63) & ~63);     // E
    uint*   bpk    = (uint*)(ssrc + E);                 // E
    ushort* T1     = (ushort*)(bpk + E);                // N*64 bf16 (T1, then T3)
    ushort* T2     = T1 + (size_t)N * FEAT;             // N*64 bf16
    ushort* w1t    = T2 + (size_t)N * FEAT;             // 64*128 bf16
    ushort* wmt    = w1t + 64 * 128;                    // 64*64 bf16
    ushort* wlt    = wmt + 64 * 64;                     // 64*64 bf16

    float* mu_out = (float*)d_out;                      // N*64
    float* ls_out = mu_out + (size_t)N * FEAT;          // N*64

    const int TB = 256;
    int grid_n4 = (N + 3) / 4;
    int grid_g  = (N + 63) / 64;

    // ---- weight prep (independent of everything) ----
    prep_w_kernel<<<8, TB, 0, stream>>>(W1, Wmu, Wls, w1t, wmt, wlt);

    // ---- CSR build (no global atomics) ----
    hist_kernel<<<SORT_BLOCKS, TB, 0, stream>>>(dst, hist, E, nb);
    colscan_kernel<<<nb, TB, 0, stream>>>(hist, btot, nb);
    bbase_kernel<<<1, TB, 0, stream>>>(btot, bbase, nb, rowptr, N, E);
    sort_scatter_kernel<<<SORT_BLOCKS, TB, 0, stream>>>(src, dst, hist, bbase, bpk, E, nb);
    place_kernel<<<nb, TB, 0, stream>>>(bpk, bbase, rowptr, dinv, ssrc, N);

    // ---- T1 = bf16(dinv * (x@W1)) via MFMA ----
    gemm1_kernel<<<grid_g, TB, 0, stream>>>(x, w1t, dinv, T1, N);

    // ---- T2 = bf16(dinv * relu(dinv*aggsum(T1) + b1)) ----
    agg_kernel<0><<<grid_n4, TB, 0, stream>>>(T1, rowptr, ssrc, dinv, b1, T2, N);

    // ---- T3 = bf16(dinv * aggsum(T2))  (reuses T1 buffer) ----
    agg_kernel<1><<<grid_n4, TB, 0, stream>>>(T2, rowptr, ssrc, dinv, nullptr, T1, N);

    // ---- heads via MFMA: mu/ls from bf16 T3 ----
    gemm_dual_kernel<<<grid_g, TB, 0, stream>>>(T1, wmt, bmu, wlt, bls, mu_out, ls_out, N);
}